// Round 1
// baseline (407.216 us; speedup 1.0000x reference)
//
#include <hip/hip_runtime.h>
#include <stdint.h>

// p = 1000003 (compile-time constant from the reference's P_PRIME); n = p-1.
#define PRIME 1000003u
#define NORD  1000002u
#define KCH   16
#define BATCH 4
#define NPATCH 784
#define LLEN  9
#define IPMAX 9000       // |<x,y>| <= 20*50*9
#define TBLN  (2*IPMAX+1)

__device__ __forceinline__ uint32_t mmul(uint32_t a, uint32_t b) {
    return (uint32_t)(((uint64_t)a * (uint64_t)b) % (uint64_t)PRIME);
}

__device__ uint32_t mpow(uint32_t base, uint32_t exp) {
    uint32_t r = 1u, b = base;
    while (exp) {
        if (exp & 1u) r = mmul(r, b);
        b = mmul(b, b);
        exp >>= 1;
    }
    return r;
}

// ---------------- Kernel 1: dlog lookup table -------------------------------
// table[g^e mod p] = e for e in [-9000, 9000]. Entries never queried are never
// written (every decrypted value is guaranteed to be g^e with |e|<=9000).
__global__ void build_table(const int* __restrict__ g_in, int* __restrict__ table) {
    int e = blockIdx.x * blockDim.x + threadIdx.x;
    if (e >= TBLN) return;
    int es = e - IPMAX;
    uint32_t exp = (es >= 0) ? (uint32_t)es : (uint32_t)(es + (int)NORD);
    uint32_t v = mpow((uint32_t)g_in[0], exp);
    table[v] = es;
}

// ---------------- Kernel 2: IPFE decrypt + dlog + dequant -------------------
// feat layout: [B][K][784] floats (transpose(1,0,2) folded into the store).
__global__ void decrypt(const int* __restrict__ ct0, const int* __restrict__ cts,
                        const int* __restrict__ y, const int* __restrict__ sk_y,
                        const float* __restrict__ bias1,
                        const int* __restrict__ table, float* __restrict__ feat) {
    int t = blockIdx.x * blockDim.x + threadIdx.x;
    if (t >= KCH * BATCH * NPATCH) return;
    int k = t / (BATCH * NPATCH);
    int r = t % (BATCH * NPATCH);
    int b = r / NPATCH;
    int j = r % NPATCH;

    const int* crow = cts + ((b * NPATCH) + j) * LLEN;
    const int* yrow = y + k * LLEN;

    uint32_t num_p = 1u, num_n = 1u;
#pragma unroll
    for (int i = 0; i < LLEN; i++) {
        int yi = yrow[i];
        uint32_t c = (uint32_t)crow[i];
        if (yi > 0)       num_p = mmul(num_p, mpow(c, (uint32_t)yi));
        else if (yi < 0)  num_n = mmul(num_n, mpow(c, (uint32_t)(-yi)));
    }
    // denom_total = ct0^sk_y * prod_{y<0} c^{|y|}; val = num_p * denom_total^(p-2)
    uint32_t den = mpow((uint32_t)ct0[b * NPATCH + j], (uint32_t)sk_y[k]);
    den = mmul(den, num_n);
    uint32_t val = mmul(num_p, mpow(den, PRIME - 2u));

    int ip = table[val];
    feat[((b * KCH) + k) * NPATCH + j] = (float)ip * 1e-4f + bias1[k];
}

// ---------------- Kernel 3: whole CNN, one block per sample -----------------
__global__ void __launch_bounds__(256) cnn(
    const float* __restrict__ feat,                 // [4][16][784]
    const float* __restrict__ bn1_g, const float* __restrict__ bn1_b,
    const float* __restrict__ bn1_m, const float* __restrict__ bn1_v,
    const float* __restrict__ conv2_w, const float* __restrict__ conv2_b,
    const float* __restrict__ bn2_g, const float* __restrict__ bn2_b,
    const float* __restrict__ bn2_m, const float* __restrict__ bn2_v,
    const float* __restrict__ conv3_w, const float* __restrict__ conv3_b,
    const float* __restrict__ bn3_g, const float* __restrict__ bn3_b,
    const float* __restrict__ bn3_m, const float* __restrict__ bn3_v,
    const float* __restrict__ fc1_w, const float* __restrict__ fc1_b,
    const float* __restrict__ fc2_w, const float* __restrict__ fc2_b,
    float* __restrict__ out) {
    const int b = blockIdx.x;
    const int tid = threadIdx.x;

    __shared__ float s1[16][14][14];   // after bn1+relu+pool
    __shared__ float s2[32][7][7];     // after conv2+bn2+relu+pool
    __shared__ float s3[576];          // after conv3+bn3+relu+pool, flat [64][3][3]
    __shared__ float h[128];           // fc1 output

    // Stage A: bn1 + relu + 2x2 maxpool  (28x28 -> 14x14)
    for (int idx = tid; idx < 16 * 14 * 14; idx += 256) {
        int c = idx / 196, pos = idx % 196;
        int oh = pos / 14, ow = pos % 14;
        float sc = bn1_g[c] * rsqrtf(bn1_v[c] + 1e-5f);
        float sh = bn1_b[c] - bn1_m[c] * sc;
        const float* fp = feat + ((b * KCH) + c) * NPATCH;
        float m = -1e30f;
#pragma unroll
        for (int dy = 0; dy < 2; dy++)
#pragma unroll
            for (int dx = 0; dx < 2; dx++) {
                float x = fp[(2 * oh + dy) * 28 + (2 * ow + dx)];
                x = fmaxf(x * sc + sh, 0.0f);
                m = fmaxf(m, x);
            }
        s1[c][oh][ow] = m;
    }
    __syncthreads();

    // Stage B: conv2(16->32, 3x3, pad 1) + bn2 + relu + pool (14 -> 7)
    for (int idx = tid; idx < 32 * 7 * 7; idx += 256) {
        int oc = idx / 49, pos = idx % 49;
        int oh = pos / 7, ow = pos % 7;
        float sc = bn2_g[oc] * rsqrtf(bn2_v[oc] + 1e-5f);
        float sh = bn2_b[oc] - bn2_m[oc] * sc;
        float mx = -1e30f;
#pragma unroll
        for (int dy = 0; dy < 2; dy++)
#pragma unroll
            for (int dx = 0; dx < 2; dx++) {
                int y0 = 2 * oh + dy, x0 = 2 * ow + dx;   // in [0,14)
                float acc = conv2_b[oc];
                for (int ic = 0; ic < 16; ic++) {
                    const float* w = conv2_w + ((oc * 16) + ic) * 9;
#pragma unroll
                    for (int kh = 0; kh < 3; kh++) {
                        int yy = y0 + kh - 1;
                        if (yy < 0 || yy >= 14) continue;
#pragma unroll
                        for (int kw = 0; kw < 3; kw++) {
                            int xx = x0 + kw - 1;
                            if (xx < 0 || xx >= 14) continue;
                            acc += s1[ic][yy][xx] * w[kh * 3 + kw];
                        }
                    }
                }
                acc = acc * sc + sh;
                mx = fmaxf(mx, fmaxf(acc, 0.0f));
            }
        s2[oc][oh][ow] = mx;
    }
    __syncthreads();

    // Stage C: conv3(32->64, 3x3, pad 1) + bn3 + relu + pool (7 -> 3)
    for (int idx = tid; idx < 64 * 3 * 3; idx += 256) {
        int oc = idx / 9, pos = idx % 9;
        int oh = pos / 3, ow = pos % 3;
        float sc = bn3_g[oc] * rsqrtf(bn3_v[oc] + 1e-5f);
        float sh = bn3_b[oc] - bn3_m[oc] * sc;
        float mx = -1e30f;
#pragma unroll
        for (int dy = 0; dy < 2; dy++)
#pragma unroll
            for (int dx = 0; dx < 2; dx++) {
                int y0 = 2 * oh + dy, x0 = 2 * ow + dx;   // in [0,6)
                float acc = conv3_b[oc];
                for (int ic = 0; ic < 32; ic++) {
                    const float* w = conv3_w + ((oc * 32) + ic) * 9;
#pragma unroll
                    for (int kh = 0; kh < 3; kh++) {
                        int yy = y0 + kh - 1;
                        if (yy < 0 || yy >= 7) continue;
#pragma unroll
                        for (int kw = 0; kw < 3; kw++) {
                            int xx = x0 + kw - 1;
                            if (xx < 0 || xx >= 7) continue;
                            acc += s2[ic][yy][xx] * w[kh * 3 + kw];
                        }
                    }
                }
                acc = acc * sc + sh;
                mx = fmaxf(mx, fmaxf(acc, 0.0f));
            }
        s3[oc * 9 + oh * 3 + ow] = mx;   // flatten order: [64][3][3]
    }
    __syncthreads();

    // Stage D: fc1 (576 -> 128) + relu
    for (int o = tid; o < 128; o += 256) {
        float acc = fc1_b[o];
        const float* w = fc1_w + o * 576;
        for (int i = 0; i < 576; i++) acc += s3[i] * w[i];
        h[o] = fmaxf(acc, 0.0f);
    }
    __syncthreads();

    // fc2 (128 -> 10)
    for (int o = tid; o < 10; o += 256) {
        float acc = fc2_b[o];
        const float* w = fc2_w + o * 128;
        for (int i = 0; i < 128; i++) acc += h[i] * w[i];
        out[b * 10 + o] = acc;
    }
}

extern "C" void kernel_launch(void* const* d_in, const int* in_sizes, int n_in,
                              void* d_out, int out_size, void* d_ws, size_t ws_size,
                              hipStream_t stream) {
    // Input order (setup_inputs dict): 0 ct0, 1 cts, 2 y, 3 sk_y, 4 bias1,
    // 5-8 bn1 g/b/m/v, 9 conv2_w, 10 conv2_b, 11-14 bn2, 15 conv3_w, 16 conv3_b,
    // 17-20 bn3, 21 fc1_w, 22 fc1_b, 23 fc2_w, 24 fc2_b, 25 g, 26 p
    const int*   ct0    = (const int*)d_in[0];
    const int*   cts    = (const int*)d_in[1];
    const int*   y      = (const int*)d_in[2];
    const int*   sk_y   = (const int*)d_in[3];
    const float* bias1  = (const float*)d_in[4];
    const float* bn1_g  = (const float*)d_in[5];
    const float* bn1_b  = (const float*)d_in[6];
    const float* bn1_m  = (const float*)d_in[7];
    const float* bn1_v  = (const float*)d_in[8];
    const float* conv2_w = (const float*)d_in[9];
    const float* conv2_b = (const float*)d_in[10];
    const float* bn2_g  = (const float*)d_in[11];
    const float* bn2_b  = (const float*)d_in[12];
    const float* bn2_m  = (const float*)d_in[13];
    const float* bn2_v  = (const float*)d_in[14];
    const float* conv3_w = (const float*)d_in[15];
    const float* conv3_b = (const float*)d_in[16];
    const float* bn3_g  = (const float*)d_in[17];
    const float* bn3_b  = (const float*)d_in[18];
    const float* bn3_m  = (const float*)d_in[19];
    const float* bn3_v  = (const float*)d_in[20];
    const float* fc1_w  = (const float*)d_in[21];
    const float* fc1_b  = (const float*)d_in[22];
    const float* fc2_w  = (const float*)d_in[23];
    const float* fc2_b  = (const float*)d_in[24];
    const int*   g_in   = (const int*)d_in[25];
    float* out = (float*)d_out;

    // Workspace layout: [0, 4000256) int32 dlog table (p entries, 4MB);
    //                   [4000256, +200704) float feat[4][16][784]
    int*   table = (int*)d_ws;
    float* feat  = (float*)((char*)d_ws + 4000256);

    build_table<<<(TBLN + 255) / 256, 256, 0, stream>>>(g_in, table);

    int ndec = KCH * BATCH * NPATCH;  // 50176
    decrypt<<<(ndec + 255) / 256, 256, 0, stream>>>(ct0, cts, y, sk_y, bias1, table, feat);

    cnn<<<BATCH, 256, 0, stream>>>(feat,
        bn1_g, bn1_b, bn1_m, bn1_v,
        conv2_w, conv2_b, bn2_g, bn2_b, bn2_m, bn2_v,
        conv3_w, conv3_b, bn3_g, bn3_b, bn3_m, bn3_v,
        fc1_w, fc1_b, fc2_w, fc2_b, out);
}

// Round 2
// 152.380 us; speedup vs baseline: 2.6724x; 2.6724x over previous
//
#include <hip/hip_runtime.h>
#include <stdint.h>

#define PRIME 1000003u
#define NORD  1000002u
#define KCH   16
#define BATCH 4
#define NPATCH 784
#define LLEN  9
#define IPMAX 9000        // |<x,y>| <= 20*50*9
#define TBLN  (2*IPMAX+1)

// Barrett reduction: M = floor(2^41 / p) = 2199016. For t < 2^40,
// q = (t*M)>>41 satisfies floor(t/p)-1 <= q <= floor(t/p), so one
// conditional subtract suffices. Low-32-bit subtract is valid since r < 2p.
__device__ __forceinline__ uint32_t mmul(uint32_t a, uint32_t b) {
    uint64_t t = (uint64_t)a * (uint64_t)b;
    uint32_t q = (uint32_t)((t * 2199016ull) >> 41);
    uint32_t r = (uint32_t)t - q * PRIME;
    return (r >= PRIME) ? r - PRIME : r;
}

__device__ uint32_t mpow(uint32_t base, uint32_t exp) {
    uint32_t r = 1u, b = base;
    while (exp) {
        if (exp & 1u) r = mmul(r, b);
        b = mmul(b, b);
        exp >>= 1;
    }
    return r;
}

// ---------------- Kernel 1: dlog lookup table -------------------------------
__global__ void build_table(const int* __restrict__ g_in, int* __restrict__ table) {
    int e = blockIdx.x * blockDim.x + threadIdx.x;
    if (e >= TBLN) return;
    int es = e - IPMAX;
    uint32_t exp = (es >= 0) ? (uint32_t)es : (uint32_t)(es + (int)NORD);
    uint32_t v = mpow((uint32_t)g_in[0], exp);
    table[v] = es;
}

// ---------------- Kernel 2: IPFE decrypt + dlog + dequant -------------------
// feat layout: [B][K][784] floats.
__global__ void decrypt(const int* __restrict__ ct0, const int* __restrict__ cts,
                        const int* __restrict__ y, const int* __restrict__ sk_y,
                        const float* __restrict__ bias1,
                        const int* __restrict__ table, float* __restrict__ feat) {
    int t = blockIdx.x * blockDim.x + threadIdx.x;
    if (t >= KCH * BATCH * NPATCH) return;
    int k = t / (BATCH * NPATCH);          // wave-uniform (3136 threads per k)
    int r = t % (BATCH * NPATCH);
    int b = r / NPATCH;
    int j = r % NPATCH;

    const int* crow = cts + ((b * NPATCH) + j) * LLEN;
    const int* yrow = y + k * LLEN;

    uint32_t num_p = 1u, num_n = 1u;
#pragma unroll
    for (int i = 0; i < LLEN; i++) {
        int yi = yrow[i];
        uint32_t c = (uint32_t)crow[i];
        if (yi > 0)       num_p = mmul(num_p, mpow(c, (uint32_t)yi));
        else if (yi < 0)  num_n = mmul(num_n, mpow(c, (uint32_t)(-yi)));
    }
    uint32_t den = mpow((uint32_t)ct0[b * NPATCH + j], (uint32_t)sk_y[k]);
    den = mmul(den, num_n);
    uint32_t val = mmul(num_p, mpow(den, PRIME - 2u));

    int ip = table[val];
    feat[((b * KCH) + k) * NPATCH + j] = (float)ip * 1e-4f + bias1[k];
}

// ---------------- Kernel 3: bn1 + relu + 2x2 maxpool (28->14) ---------------
// s1g layout: [B][16][14][14]
__global__ void __launch_bounds__(256) stage1(
    const float* __restrict__ feat,
    const float* __restrict__ bn1_g, const float* __restrict__ bn1_b,
    const float* __restrict__ bn1_m, const float* __restrict__ bn1_v,
    float* __restrict__ s1g) {
    int idx = blockIdx.x * 256 + threadIdx.x;
    if (idx >= BATCH * 16 * 196) return;
    int b = idx / (16 * 196);
    int r = idx % (16 * 196);
    int c = r / 196;
    int pos = r % 196;
    int oh = pos / 14, ow = pos % 14;
    float sc = bn1_g[c] * rsqrtf(bn1_v[c] + 1e-5f);
    float sh = bn1_b[c] - bn1_m[c] * sc;
    const float* fp = feat + ((b * KCH) + c) * NPATCH;
    float x00 = fp[(2 * oh) * 28 + 2 * ow];
    float x01 = fp[(2 * oh) * 28 + 2 * ow + 1];
    float x10 = fp[(2 * oh + 1) * 28 + 2 * ow];
    float x11 = fp[(2 * oh + 1) * 28 + 2 * ow + 1];
    float m = fmaxf(fmaxf(x00, x01), fmaxf(x10, x11));
    s1g[idx] = fmaxf(m * sc + sh, 0.0f);   // monotone: bn-scale>0? not guaranteed...
}

// NOTE: bn scale can be negative (g ~ N(1,0.1) so >0 with these inputs, but be
// safe): apply bn before max. Replaced below — see stage1_safe.
__global__ void __launch_bounds__(256) stage1_safe(
    const float* __restrict__ feat,
    const float* __restrict__ bn1_g, const float* __restrict__ bn1_b,
    const float* __restrict__ bn1_m, const float* __restrict__ bn1_v,
    float* __restrict__ s1g) {
    int idx = blockIdx.x * 256 + threadIdx.x;
    if (idx >= BATCH * 16 * 196) return;
    int b = idx / (16 * 196);
    int r = idx % (16 * 196);
    int c = r / 196;
    int pos = r % 196;
    int oh = pos / 14, ow = pos % 14;
    float sc = bn1_g[c] * rsqrtf(bn1_v[c] + 1e-5f);
    float sh = bn1_b[c] - bn1_m[c] * sc;
    const float* fp = feat + ((b * KCH) + c) * NPATCH;
    float m = -1e30f;
#pragma unroll
    for (int dy = 0; dy < 2; dy++)
#pragma unroll
        for (int dx = 0; dx < 2; dx++) {
            float x = fp[(2 * oh + dy) * 28 + (2 * ow + dx)];
            m = fmaxf(m, fmaxf(x * sc + sh, 0.0f));
        }
    s1g[idx] = m;
}

// ---------------- Kernel 4: conv2 + bn2 + relu + pool (14->7) ---------------
// block = (b, oc): 4*32 = 128 blocks x 256 threads. s2g: [B][32][7][7]
__global__ void __launch_bounds__(256) conv2_k(
    const float* __restrict__ s1g,
    const float* __restrict__ conv2_w, const float* __restrict__ conv2_b,
    const float* __restrict__ bn2_g, const float* __restrict__ bn2_b,
    const float* __restrict__ bn2_m, const float* __restrict__ bn2_v,
    float* __restrict__ s2g) {
    const int b  = blockIdx.x >> 5;
    const int oc = blockIdx.x & 31;
    const int tid = threadIdx.x;

    __shared__ float s1p[16][16][16];   // padded (halo of zeros), 16 KB
    __shared__ float w[16 * 9];
    __shared__ float co[196];

    for (int i = tid; i < 16 * 16 * 16; i += 256)
        ((float*)s1p)[i] = 0.0f;
    if (tid < 144) w[tid] = conv2_w[oc * 144 + tid];
    __syncthreads();
    for (int i = tid; i < 16 * 196; i += 256) {
        int ic = i / 196, pos = i % 196;
        int yy = pos / 14, xx = pos % 14;
        s1p[ic][yy + 1][xx + 1] = s1g[((b * 16 + ic) * 196) + pos];
    }
    __syncthreads();

    if (tid < 196) {
        int oh = tid / 14, ow = tid % 14;
        float a0 = 0.0f, a1 = 0.0f, a2 = 0.0f;
#pragma unroll
        for (int ic = 0; ic < 16; ic++) {
            const float* wp = &w[ic * 9];
            const float* sp = &s1p[ic][oh][ow];
            a0 = fmaf(sp[0],  wp[0], fmaf(sp[1],  wp[1], fmaf(sp[2],  wp[2], a0)));
            a1 = fmaf(sp[16], wp[3], fmaf(sp[17], wp[4], fmaf(sp[18], wp[5], a1)));
            a2 = fmaf(sp[32], wp[6], fmaf(sp[33], wp[7], fmaf(sp[34], wp[8], a2)));
        }
        float sc = bn2_g[oc] * rsqrtf(bn2_v[oc] + 1e-5f);
        float sh = bn2_b[oc] - bn2_m[oc] * sc;
        float acc = (a0 + a1 + a2 + conv2_b[oc]) * sc + sh;
        co[tid] = fmaxf(acc, 0.0f);
    }
    __syncthreads();

    if (tid < 49) {
        int oh = tid / 7, ow = tid % 7;
        const float* c0 = &co[(2 * oh) * 14 + 2 * ow];
        float mx = fmaxf(fmaxf(c0[0], c0[1]), fmaxf(c0[14], c0[15]));
        s2g[((b * 32 + oc) * 49) + tid] = mx;
    }
}

// ---------------- Kernel 5: conv3 + bn3 + relu + pool (7->3) ----------------
// block = (b, oc): 4*64 = 256 blocks x 64 threads. s3g: [B][576] flat [64][3][3]
__global__ void __launch_bounds__(64) conv3_k(
    const float* __restrict__ s2g,
    const float* __restrict__ conv3_w, const float* __restrict__ conv3_b,
    const float* __restrict__ bn3_g, const float* __restrict__ bn3_b,
    const float* __restrict__ bn3_m, const float* __restrict__ bn3_v,
    float* __restrict__ s3g) {
    const int b  = blockIdx.x >> 6;
    const int oc = blockIdx.x & 63;
    const int tid = threadIdx.x;

    __shared__ float s2p[32][9][9];    // padded, 10.1 KB
    __shared__ float w[32 * 9];
    __shared__ float co[49];

    for (int i = tid; i < 32 * 81; i += 64)
        ((float*)s2p)[i] = 0.0f;
    for (int i = tid; i < 288; i += 64) w[i] = conv3_w[oc * 288 + i];
    __syncthreads();
    for (int i = tid; i < 32 * 49; i += 64) {
        int ic = i / 49, pos = i % 49;
        int yy = pos / 7, xx = pos % 7;
        s2p[ic][yy + 1][xx + 1] = s2g[((b * 32 + ic) * 49) + pos];
    }
    __syncthreads();

    if (tid < 49) {
        int oh = tid / 7, ow = tid % 7;
        float a0 = 0.0f, a1 = 0.0f, a2 = 0.0f;
#pragma unroll
        for (int ic = 0; ic < 32; ic++) {
            const float* wp = &w[ic * 9];
            const float* sp = &s2p[ic][oh][ow];
            a0 = fmaf(sp[0],  wp[0], fmaf(sp[1],  wp[1], fmaf(sp[2],  wp[2], a0)));
            a1 = fmaf(sp[9],  wp[3], fmaf(sp[10], wp[4], fmaf(sp[11], wp[5], a1)));
            a2 = fmaf(sp[18], wp[6], fmaf(sp[19], wp[7], fmaf(sp[20], wp[8], a2)));
        }
        float sc = bn3_g[oc] * rsqrtf(bn3_v[oc] + 1e-5f);
        float sh = bn3_b[oc] - bn3_m[oc] * sc;
        float acc = (a0 + a1 + a2 + conv3_b[oc]) * sc + sh;
        co[tid] = fmaxf(acc, 0.0f);
    }
    __syncthreads();

    if (tid < 9) {
        int oh = tid / 3, ow = tid % 3;               // pool windows at rows {0,2,4}
        const float* c0 = &co[(2 * oh) * 7 + 2 * ow];
        float mx = fmaxf(fmaxf(c0[0], c0[1]), fmaxf(c0[7], c0[8]));
        s3g[b * 576 + oc * 9 + tid] = mx;
    }
}

// ---------------- Kernel 6: fc1 + relu + fc2 --------------------------------
__global__ void __launch_bounds__(128) fc_k(
    const float* __restrict__ s3g,
    const float* __restrict__ fc1_w, const float* __restrict__ fc1_b,
    const float* __restrict__ fc2_w, const float* __restrict__ fc2_b,
    float* __restrict__ out) {
    const int b = blockIdx.x;
    const int tid = threadIdx.x;
    __shared__ float s3[576];
    __shared__ float h[128];

    for (int i = tid; i < 576; i += 128) s3[i] = s3g[b * 576 + i];
    __syncthreads();

    {   // fc1: each of 128 threads computes one output, 4 accumulators
        float a0 = 0.0f, a1 = 0.0f, a2 = 0.0f, a3 = 0.0f;
        const float* w = fc1_w + tid * 576;
        for (int i = 0; i < 576; i += 4) {
            a0 = fmaf(s3[i],     w[i],     a0);
            a1 = fmaf(s3[i + 1], w[i + 1], a1);
            a2 = fmaf(s3[i + 2], w[i + 2], a2);
            a3 = fmaf(s3[i + 3], w[i + 3], a3);
        }
        h[tid] = fmaxf(a0 + a1 + a2 + a3 + fc1_b[tid], 0.0f);
    }
    __syncthreads();

    if (tid < 10) {
        float a0 = 0.0f, a1 = 0.0f;
        const float* w = fc2_w + tid * 128;
        for (int i = 0; i < 128; i += 2) {
            a0 = fmaf(h[i],     w[i],     a0);
            a1 = fmaf(h[i + 1], w[i + 1], a1);
        }
        out[b * 10 + tid] = a0 + a1 + fc2_b[tid];
    }
}

extern "C" void kernel_launch(void* const* d_in, const int* in_sizes, int n_in,
                              void* d_out, int out_size, void* d_ws, size_t ws_size,
                              hipStream_t stream) {
    const int*   ct0    = (const int*)d_in[0];
    const int*   cts    = (const int*)d_in[1];
    const int*   y      = (const int*)d_in[2];
    const int*   sk_y   = (const int*)d_in[3];
    const float* bias1  = (const float*)d_in[4];
    const float* bn1_g  = (const float*)d_in[5];
    const float* bn1_b  = (const float*)d_in[6];
    const float* bn1_m  = (const float*)d_in[7];
    const float* bn1_v  = (const float*)d_in[8];
    const float* conv2_w = (const float*)d_in[9];
    const float* conv2_b = (const float*)d_in[10];
    const float* bn2_g  = (const float*)d_in[11];
    const float* bn2_b  = (const float*)d_in[12];
    const float* bn2_m  = (const float*)d_in[13];
    const float* bn2_v  = (const float*)d_in[14];
    const float* conv3_w = (const float*)d_in[15];
    const float* conv3_b = (const float*)d_in[16];
    const float* bn3_g  = (const float*)d_in[17];
    const float* bn3_b  = (const float*)d_in[18];
    const float* bn3_m  = (const float*)d_in[19];
    const float* bn3_v  = (const float*)d_in[20];
    const float* fc1_w  = (const float*)d_in[21];
    const float* fc1_b  = (const float*)d_in[22];
    const float* fc2_w  = (const float*)d_in[23];
    const float* fc2_b  = (const float*)d_in[24];
    const int*   g_in   = (const int*)d_in[25];
    float* out = (float*)d_out;

    // Workspace layout (bytes):
    //   [0,        4000256)  int32 dlog table (p entries)
    //   [4000256,  4200960)  float feat [4][16][784]
    //   [4200960,  4251136)  float s1g  [4][16][14][14]
    //   [4251136,  4276224)  float s2g  [4][32][7][7]
    //   [4276224,  4285440)  float s3g  [4][576]
    char* ws = (char*)d_ws;
    int*   table = (int*)ws;
    float* feat  = (float*)(ws + 4000256);
    float* s1g   = (float*)(ws + 4200960);
    float* s2g   = (float*)(ws + 4251136);
    float* s3g   = (float*)(ws + 4276224);

    build_table<<<(TBLN + 255) / 256, 256, 0, stream>>>(g_in, table);

    int ndec = KCH * BATCH * NPATCH;  // 50176
    decrypt<<<(ndec + 255) / 256, 256, 0, stream>>>(ct0, cts, y, sk_y, bias1, table, feat);

    stage1_safe<<<(BATCH * 16 * 196 + 255) / 256, 256, 0, stream>>>(
        feat, bn1_g, bn1_b, bn1_m, bn1_v, s1g);

    conv2_k<<<BATCH * 32, 256, 0, stream>>>(
        s1g, conv2_w, conv2_b, bn2_g, bn2_b, bn2_m, bn2_v, s2g);

    conv3_k<<<BATCH * 64, 64, 0, stream>>>(
        s2g, conv3_w, conv3_b, bn3_g, bn3_b, bn3_m, bn3_v, s3g);

    fc_k<<<BATCH, 128, 0, stream>>>(s3g, fc1_w, fc1_b, fc2_w, fc2_b, out);
}